// Round 5
// baseline (696.781 us; speedup 1.0000x reference)
//
#include <hip/hip_runtime.h>

// Hungarian (e-maxx shortest-augmenting-path), 32 independent 128x128 L1
// assignment problems. ONE WAVE per problem, 2 columns per lane, zero LDS,
// zero barriers, bit-exact fp trajectory vs the JAX reference.
//
// R3 lesson: trajectory must be bit-exact (no algorithmic reordering).
// R4->R5 (chain micro-opts, all value-preserving):
//  * poison-minv: used columns get minv=BIGF at mark time (decays by -delta
//    each iter, stays ~1e9 >> any real reduced cost, never read as a value;
//    way[] of used cols protected by the !used guard). Removes the per-iter
//    used-masking cndmask AND the conditional minv update from the chain.
//  * minv update via fminf (bit-identical: no NaN; cur = -0 impossible here),
//    way-compare moves off the critical chain.
//  * fetch of column j1's row state: 8 direct v_readlane from STABLE vgprs
//    (no VALU-write->readlane hazard) + scalar selects.
// Pairing 2 problems/wave was considered and rejected: all problems already
// run concurrently on separate CUs; wall time = slowest solve x step latency.

#define NN 128
#define BIGF 1e9f

__device__ __forceinline__ int rl_i(int x, int l) {
    return __builtin_amdgcn_readlane(x, l);
}
__device__ __forceinline__ float rl_f(float x, int l) {
    return __uint_as_float((uint32_t)__builtin_amdgcn_readlane((int)__float_as_uint(x), l));
}

template <int CTRL, int RM>
__device__ __forceinline__ float dpp_min_f(float x) {
    int xi = (int)__float_as_uint(x);
    float s = __uint_as_float((uint32_t)__builtin_amdgcn_update_dpp(xi, xi, CTRL, RM, 0xf, false));
    return fminf(x, s);
}

// full-wave (64-lane) f32 min, made uniform via readlane(63)
__device__ __forceinline__ float wave_min_f(float x) {
    x = dpp_min_f<0x111, 0xf>(x);  // row_shr:1
    x = dpp_min_f<0x112, 0xf>(x);  // row_shr:2
    x = dpp_min_f<0x114, 0xf>(x);  // row_shr:4
    x = dpp_min_f<0x118, 0xf>(x);  // row_shr:8
    x = dpp_min_f<0x142, 0xa>(x);  // row_bcast15 (rows 1,3)
    x = dpp_min_f<0x143, 0xc>(x);  // row_bcast31 (rows 2,3)
    return rl_f(x, 63);
}

__global__ __launch_bounds__(64) void hungarian_kernel(
    const float* __restrict__ preds,
    const float* __restrict__ targets,
    int* __restrict__ out)
{
    const int prob = blockIdx.x;
    const int lane = threadIdx.x;

    const float2* p2 = (const float2*)preds + prob * NN;
    const float2* t2 = (const float2*)targets + prob * NN;

    float2 qav = p2[lane], qbv = p2[lane + 64];
    float2 tav = t2[lane], tbv = t2[lane + 64];
    const float qrx0 = qav.x, qrx1 = qbv.x;
    const float qry0 = qav.y, qry1 = qbv.y;
    const float tx0  = tav.x, tx1  = tbv.x;
    const float ty0  = tav.y, ty1  = tbv.y;
    const int   col0 = lane + 1, col1 = lane + 65;

    float v0 = 0.f, v1 = 0.f;       // column duals (reference: start 0)
    float w0 = 0.f, w1 = 0.f;       // u[p[col]] cache (valid when p != 0)
    float qcx0 = 0.f, qcx1 = 0.f;   // pred x of row p[col]
    float qcy0 = 0.f, qcy1 = 0.f;   // pred y of row p[col]
    int   p0 = 0, p1 = 0;           // matched row (1-indexed), 0 = free

    for (int i = 0; i < NN; ++i) {
        // coords of current row i (uniform): stable-source readlanes + cselect
        const float qxa = rl_f(qrx0, i & 63), qxb = rl_f(qrx1, i & 63);
        const float qya = rl_f(qry0, i & 63), qyb = rl_f(qry1, i & 63);
        const float qix = (i & 64) ? qxb : qxa;
        const float qiy = (i & 64) ? qyb : qya;

        // ---- specialized first search step: j0 = 0, nothing used ----
        // cur = (cost - u[i+1]) - v with u[i+1] = +0  ->  cost - v (bit-exact)
        float minv0 = (fabsf(qix - tx0) + fabsf(qiy - ty0)) - v0;
        float minv1 = (fabsf(qix - tx1) + fabsf(qiy - ty1)) - v1;
        int   way0 = 0, way1 = 0;
        bool  used0 = false, used1 = false;

        float m     = fminf(minv0, minv1);
        float delta = wave_min_f(m);
        unsigned long long b0 = __ballot(minv0 == delta);
        unsigned long long b1 = __ballot(minv1 == delta);
        int j1 = b0 ? (int)__ffsll((long long)b0) : 64 + (int)__ffsll((long long)b1);

        int  src = (j1 - 1) & 63;
        bool hi  = j1 > 64;
        {
            // stable-source fetch (p/w/qc last written in previous augment)
            int   pa = rl_i(p0, src),   pb = rl_i(p1, src);
            float wa = rl_f(w0, src),   wb = rl_f(w1, src);
            float xa = rl_f(qcx0, src), xb = rl_f(qcx1, src);
            float ya = rl_f(qcy0, src), yb = rl_f(qcy1, src);
            int   i0n = hi ? pb : pa;
            float u_n = hi ? wb : wa;
            float cqx = hi ? xb : xa;
            float cqy = hi ? yb : ya;

            // step-0 updates: nothing used -> v,w unchanged; minv -= delta
            minv0 -= delta;
            minv1 -= delta;
            float u_row = delta;          // u[i+1] = 0 + delta (exact)
            int   j0    = j1;
            float u_j0  = u_n;

            if (i0n != 0) {
                for (int it = 0; it < NN + 2; ++it) {
                    // mark used[j0] and poison its minv (never read as value)
                    const bool mk0 = (col0 == j0), mk1 = (col1 == j0);
                    used0 |= mk0; used1 |= mk1;
                    minv0 = mk0 ? BIGF : minv0;
                    minv1 = mk1 ? BIGF : minv1;

                    const float cur0 = ((fabsf(cqx - tx0) + fabsf(cqy - ty0)) - u_j0) - v0;
                    const float cur1 = ((fabsf(cqx - tx1) + fabsf(cqy - ty1)) - u_j0) - v1;

                    // way update (off the value chain; guard matches reference)
                    if (!used0 && cur0 < minv0) way0 = j0;
                    if (!used1 && cur1 < minv1) way1 = j0;

                    // minv = fminf(masked cur, minv)  (bit-identical to ref)
                    const float ce0 = used0 ? BIGF : cur0;
                    const float ce1 = used1 ? BIGF : cur1;
                    minv0 = fminf(ce0, minv0);
                    minv1 = fminf(ce1, minv1);

                    // argmin (first-index, jnp semantics; used cols ~1e9 never win)
                    m     = fminf(minv0, minv1);
                    delta = wave_min_f(m);
                    b0 = __ballot(minv0 == delta);
                    b1 = __ballot(minv1 == delta);
                    j1 = b0 ? (int)__ffsll((long long)b0) : 64 + (int)__ffsll((long long)b1);

                    src = (j1 - 1) & 63;
                    hi  = j1 > 64;
                    const int   pa2 = rl_i(p0, src),   pb2 = rl_i(p1, src);
                    const float wa2 = rl_f(w0, src),   wb2 = rl_f(w1, src);
                    const float xa2 = rl_f(qcx0, src), xb2 = rl_f(qcx1, src);
                    const float ya2 = rl_f(qcy0, src), yb2 = rl_f(qcy1, src);
                    i0n = hi ? pb2 : pa2;
                    const float u_nn = hi ? wb2 : wa2;
                    const float nqx  = hi ? xb2 : xa2;
                    const float nqy  = hi ? yb2 : ya2;

                    // reference-exact dual updates: v -= du, u[p] += du,
                    // minv -= delta (unused cols: exact; used: decays poison)
                    const float td0 = used0 ? delta : 0.f;
                    const float td1 = used1 ? delta : 0.f;
                    v0 -= td0; w0 += td0;
                    v1 -= td1; w1 += td1;
                    minv0 -= delta;
                    minv1 -= delta;
                    u_row += delta;

                    j0 = j1; u_j0 = u_nn; cqx = nqx; cqy = nqy;
                    if (i0n == 0) break;
                }
            }

            // ---- augment: shuffle (p, w, qc) along `way` chain from j0 ----
            int jj = j0;
            for (int it = 0; it <= NN; ++it) {
                const int  wsrc = (jj - 1) & 63;
                const bool whi  = jj > 64;
                const int  wva = rl_i(way0, wsrc), wvb = rl_i(way1, wsrc);
                const int  jn  = whi ? wvb : wva;

                int pn; float wn, xn, yn;
                if (jn == 0) {                      // path root: current row
                    pn = i + 1; wn = u_row; xn = qix; yn = qiy;
                } else {
                    const int  s2 = (jn - 1) & 63;
                    const bool h2 = jn > 64;
                    const int   paa = rl_i(p0, s2),   pbb = rl_i(p1, s2);
                    const float waa = rl_f(w0, s2),   wbb = rl_f(w1, s2);
                    const float xaa = rl_f(qcx0, s2), xbb = rl_f(qcx1, s2);
                    const float yaa = rl_f(qcy0, s2), ybb = rl_f(qcy1, s2);
                    pn = h2 ? pbb : paa; wn = h2 ? wbb : waa;
                    xn = h2 ? xbb : xaa; yn = h2 ? ybb : yaa;
                }
                if (col0 == jj) { p0 = pn; w0 = wn; qcx0 = xn; qcy0 = yn; }
                if (col1 == jj) { p1 = pn; w1 = wn; qcx1 = xn; qcy1 = yn; }
                jj = jn;
                if (jj == 0) break;
            }
        }
    }

    // p_[s] = row matched to column col[s]; out[row] = col (0-indexed)
    out[prob * NN + p0 - 1] = col0 - 1;
    out[prob * NN + p1 - 1] = col1 - 1;
}

extern "C" void kernel_launch(void* const* d_in, const int* in_sizes, int n_in,
                              void* d_out, int out_size, void* d_ws, size_t ws_size,
                              hipStream_t stream) {
    const float* preds   = (const float*)d_in[0];   // (4,8,128,2) fp32
    const float* targets = (const float*)d_in[1];   // (4,8,128,2) fp32
    int* out = (int*)d_out;                         // (4,8,128) int32

    hungarian_kernel<<<32, 64, 0, stream>>>(preds, targets, out);
}

// Round 6
// 633.576 us; speedup vs baseline: 1.0998x; 1.0998x over previous
//
#include <hip/hip_runtime.h>

// Hungarian (e-maxx shortest-augmenting-path), 32 independent 128x128 L1
// assignment problems. ONE WAVE per problem, 2 columns per lane, zero LDS,
// zero barriers, bit-exact fp trajectory vs the JAX reference.
//
// R3 lesson: trajectory must be bit-exact (no algorithmic reordering).
// R5 lesson: poison-minv + 8-readlane fetch regressed (565->645us); reverted.
// R6 = R4 (565us) + (a) while(true) with 2x manual unroll (halves branch
// overhead), (b) src/hi/j1 taken directly from the ffs results (shorter
// scalar path into the fetch). No fp op changes.

#define NN 128
#define BIGF 1e9f

__device__ __forceinline__ int rl_i(int x, int l) {
    return __builtin_amdgcn_readlane(x, l);
}
__device__ __forceinline__ float rl_f(float x, int l) {
    return __uint_as_float((uint32_t)__builtin_amdgcn_readlane((int)__float_as_uint(x), l));
}

template <int CTRL, int RM>
__device__ __forceinline__ float dpp_min_f(float x) {
    int xi = (int)__float_as_uint(x);
    float s = __uint_as_float((uint32_t)__builtin_amdgcn_update_dpp(xi, xi, CTRL, RM, 0xf, false));
    return fminf(x, s);
}

// full-wave (64-lane) f32 min, made uniform via readlane(63)
__device__ __forceinline__ float wave_min_f(float x) {
    x = dpp_min_f<0x111, 0xf>(x);  // row_shr:1
    x = dpp_min_f<0x112, 0xf>(x);  // row_shr:2
    x = dpp_min_f<0x114, 0xf>(x);  // row_shr:4
    x = dpp_min_f<0x118, 0xf>(x);  // row_shr:8
    x = dpp_min_f<0x142, 0xa>(x);  // row_bcast15 (rows 1,3)
    x = dpp_min_f<0x143, 0xc>(x);  // row_bcast31 (rows 2,3)
    return rl_f(x, 63);
}

__global__ __launch_bounds__(64) void hungarian_kernel(
    const float* __restrict__ preds,
    const float* __restrict__ targets,
    int* __restrict__ out)
{
    const int prob = blockIdx.x;
    const int lane = threadIdx.x;

    const float2* p2 = (const float2*)preds + prob * NN;
    const float2* t2 = (const float2*)targets + prob * NN;

    float2 qav = p2[lane], qbv = p2[lane + 64];
    float2 tav = t2[lane], tbv = t2[lane + 64];
    const float qrx0 = qav.x, qrx1 = qbv.x;
    const float qry0 = qav.y, qry1 = qbv.y;
    const float tx0  = tav.x, tx1  = tbv.x;
    const float ty0  = tav.y, ty1  = tbv.y;
    const int   col0 = lane + 1, col1 = lane + 65;

    float v0 = 0.f, v1 = 0.f;       // column duals (reference: start 0)
    float w0 = 0.f, w1 = 0.f;       // u[p[col]] cache (valid when p != 0)
    float qcx0 = 0.f, qcx1 = 0.f;   // pred x of row p[col]
    float qcy0 = 0.f, qcy1 = 0.f;   // pred y of row p[col]
    int   p0 = 0, p1 = 0;           // matched row (1-indexed), 0 = free

    for (int i = 0; i < NN; ++i) {
        // coords of current row i (uniform via readlane + uniform select)
        const float qxa = rl_f(qrx0, i & 63), qxb = rl_f(qrx1, i & 63);
        const float qya = rl_f(qry0, i & 63), qyb = rl_f(qry1, i & 63);
        const float qix = (i & 64) ? qxb : qxa;
        const float qiy = (i & 64) ? qyb : qya;

        // ---- specialized first search step: j0 = 0, nothing used ----
        // cur = (cost - u[i+1]) - v with u[i+1] = +0  ->  cost - v (bit-exact)
        float minv0 = (fabsf(qix - tx0) + fabsf(qiy - ty0)) - v0;
        float minv1 = (fabsf(qix - tx1) + fabsf(qiy - ty1)) - v1;
        int   way0 = 0, way1 = 0;
        bool  used0 = false, used1 = false;

        float m     = fminf(minv0, minv1);
        float delta = wave_min_f(m);
        unsigned long long b0 = __ballot(minv0 == delta);
        unsigned long long b1 = __ballot(minv1 == delta);
        int  f0  = (int)__ffsll((long long)b0);
        int  f1  = (int)__ffsll((long long)b1);
        bool hi  = (b0 == 0);
        int  j1  = hi ? 64 + f1 : f0;
        int  src = (hi ? f1 : f0) - 1;

        int   i0n = rl_i(hi ? p1 : p0, src);
        float u_n = rl_f(hi ? w1 : w0, src);
        float cqx = rl_f(hi ? qcx1 : qcx0, src);
        float cqy = rl_f(hi ? qcy1 : qcy0, src);

        // step-0 updates: nothing used -> v,w unchanged; minv -= delta
        minv0 -= delta;
        minv1 -= delta;
        float u_row = delta;          // u[i+1] = 0 + delta (exact)
        int   j0    = j1;
        float u_j0  = u_n;

        // ---- inner Dijkstra steps (R4 body, 2x unrolled) ----
#define SAP_STEP                                                               \
        {                                                                      \
            used0 = used0 | (col0 == j0);                                      \
            used1 = used1 | (col1 == j0);                                      \
                                                                               \
            const float cur0 = ((fabsf(cqx - tx0) + fabsf(cqy - ty0)) - u_j0) - v0; \
            const float cur1 = ((fabsf(cqx - tx1) + fabsf(cqy - ty1)) - u_j0) - v1; \
            if (!used0 && cur0 < minv0) { minv0 = cur0; way0 = j0; }           \
            if (!used1 && cur1 < minv1) { minv1 = cur1; way1 = j0; }           \
            const float mv0 = used0 ? BIGF : minv0;                            \
            const float mv1 = used1 ? BIGF : minv1;                            \
                                                                               \
            m     = fminf(mv0, mv1);                                           \
            delta = wave_min_f(m);                                             \
            b0 = __ballot(mv0 == delta);                                       \
            b1 = __ballot(mv1 == delta);                                       \
            f0  = (int)__ffsll((long long)b0);                                 \
            f1  = (int)__ffsll((long long)b1);                                 \
            hi  = (b0 == 0);                                                   \
            j1  = hi ? 64 + f1 : f0;                                           \
            src = (hi ? f1 : f0) - 1;                                          \
                                                                               \
            i0n = rl_i(hi ? p1 : p0, src);                                     \
            const float u_nn = rl_f(hi ? w1 : w0, src);                        \
            const float nqx  = rl_f(hi ? qcx1 : qcx0, src);                    \
            const float nqy  = rl_f(hi ? qcy1 : qcy0, src);                    \
                                                                               \
            const float td0 = used0 ? delta : 0.f;                             \
            const float td1 = used1 ? delta : 0.f;                             \
            v0 -= td0; w0 += td0;                                              \
            v1 -= td1; w1 += td1;                                              \
            minv0 -= used0 ? 0.f : delta;                                      \
            minv1 -= used1 ? 0.f : delta;                                      \
            u_row += delta;                                                    \
                                                                               \
            j0 = j1; u_j0 = u_nn; cqx = nqx; cqy = nqy;                        \
        }

        if (i0n != 0) {
            while (true) {
                SAP_STEP;
                if (i0n == 0) break;
                SAP_STEP;
                if (i0n == 0) break;
            }
        }
#undef SAP_STEP

        // ---- augment: shuffle (p, w, qc) along `way` chain from j0 ----
        int jj = j0;
        for (int it = 0; it <= NN; ++it) {
            const int  wsrc = (jj - 1) & 63;
            const bool whi  = jj > 64;
            const int  wva = rl_i(way0, wsrc), wvb = rl_i(way1, wsrc);
            const int  jn  = whi ? wvb : wva;

            int pn; float wn, xn, yn;
            if (jn == 0) {                      // path root: current row
                pn = i + 1; wn = u_row; xn = qix; yn = qiy;
            } else {
                const int  s2 = (jn - 1) & 63;
                const bool h2 = jn > 64;
                const int   paa = rl_i(p0, s2),   pbb = rl_i(p1, s2);
                const float waa = rl_f(w0, s2),   wbb = rl_f(w1, s2);
                const float xaa = rl_f(qcx0, s2), xbb = rl_f(qcx1, s2);
                const float yaa = rl_f(qcy0, s2), ybb = rl_f(qcy1, s2);
                pn = h2 ? pbb : paa; wn = h2 ? wbb : waa;
                xn = h2 ? xbb : xaa; yn = h2 ? ybb : yaa;
            }
            if (col0 == jj) { p0 = pn; w0 = wn; qcx0 = xn; qcy0 = yn; }
            if (col1 == jj) { p1 = pn; w1 = wn; qcx1 = xn; qcy1 = yn; }
            jj = jn;
            if (jj == 0) break;
        }
    }

    // p_[s] = row matched to column col[s]; out[row] = col (0-indexed)
    out[prob * NN + p0 - 1] = col0 - 1;
    out[prob * NN + p1 - 1] = col1 - 1;
}

extern "C" void kernel_launch(void* const* d_in, const int* in_sizes, int n_in,
                              void* d_out, int out_size, void* d_ws, size_t ws_size,
                              hipStream_t stream) {
    const float* preds   = (const float*)d_in[0];   // (4,8,128,2) fp32
    const float* targets = (const float*)d_in[1];   // (4,8,128,2) fp32
    int* out = (int*)d_out;                         // (4,8,128) int32

    hungarian_kernel<<<32, 64, 0, stream>>>(preds, targets, out);
}

// Round 7
// 612.085 us; speedup vs baseline: 1.1384x; 1.0351x over previous
//
#include <hip/hip_runtime.h>

// Hungarian (e-maxx shortest-augmenting-path), 32 independent 128x128 L1
// assignment problems. ONE WAVE per problem, 2 columns per lane, zero LDS,
// zero barriers, bit-exact fp trajectory vs the JAX reference.
//
// R3 lesson: trajectory must be bit-exact (no algorithmic reordering).
// R5 lesson: poison-minv + 8-readlane fetch together regressed; R6 lesson:
// loop-skeleton rewrites (2x unroll, ffs index math) regressed 3% — the R4
// codegen is a scheduling local optimum. R7 = R4 byte-exact EXCEPT the
// poison-minv transform alone (shorter argmin chain):
//   * on marking j0 used: minv[j0] = BIGF (decays by -delta each iter; stays
//     ~1e9 >> delta <= ~4, never wins argmin, never equals delta in ballot)
//   * argmin input = minv directly (removes 2 mask-cndmasks on the chain)
//   * minv update = fminf(used?BIG:cur, minv)  (bit-identical for unused)
//   * minv -= delta unconditional (removes 2 cndmasks)

#define NN 128
#define BIGF 1e9f

__device__ __forceinline__ int rl_i(int x, int l) {
    return __builtin_amdgcn_readlane(x, l);
}
__device__ __forceinline__ float rl_f(float x, int l) {
    return __uint_as_float((uint32_t)__builtin_amdgcn_readlane((int)__float_as_uint(x), l));
}

template <int CTRL, int RM>
__device__ __forceinline__ float dpp_min_f(float x) {
    int xi = (int)__float_as_uint(x);
    float s = __uint_as_float((uint32_t)__builtin_amdgcn_update_dpp(xi, xi, CTRL, RM, 0xf, false));
    return fminf(x, s);
}

// full-wave (64-lane) f32 min, made uniform via readlane(63)
__device__ __forceinline__ float wave_min_f(float x) {
    x = dpp_min_f<0x111, 0xf>(x);  // row_shr:1
    x = dpp_min_f<0x112, 0xf>(x);  // row_shr:2
    x = dpp_min_f<0x114, 0xf>(x);  // row_shr:4
    x = dpp_min_f<0x118, 0xf>(x);  // row_shr:8
    x = dpp_min_f<0x142, 0xa>(x);  // row_bcast15 (rows 1,3)
    x = dpp_min_f<0x143, 0xc>(x);  // row_bcast31 (rows 2,3)
    return rl_f(x, 63);
}

__global__ __launch_bounds__(64) void hungarian_kernel(
    const float* __restrict__ preds,
    const float* __restrict__ targets,
    int* __restrict__ out)
{
    const int prob = blockIdx.x;
    const int lane = threadIdx.x;

    const float2* p2 = (const float2*)preds + prob * NN;
    const float2* t2 = (const float2*)targets + prob * NN;

    float2 qav = p2[lane], qbv = p2[lane + 64];
    float2 tav = t2[lane], tbv = t2[lane + 64];
    const float qrx0 = qav.x, qrx1 = qbv.x;
    const float qry0 = qav.y, qry1 = qbv.y;
    const float tx0  = tav.x, tx1  = tbv.x;
    const float ty0  = tav.y, ty1  = tbv.y;
    const int   col0 = lane + 1, col1 = lane + 65;

    float v0 = 0.f, v1 = 0.f;       // column duals (reference: start 0)
    float w0 = 0.f, w1 = 0.f;       // u[p[col]] cache (valid when p != 0)
    float qcx0 = 0.f, qcx1 = 0.f;   // pred x of row p[col]
    float qcy0 = 0.f, qcy1 = 0.f;   // pred y of row p[col]
    int   p0 = 0, p1 = 0;           // matched row (1-indexed), 0 = free

    for (int i = 0; i < NN; ++i) {
        // coords of current row i (uniform): stable-source readlanes + cselect
        const float qxa = rl_f(qrx0, i & 63), qxb = rl_f(qrx1, i & 63);
        const float qya = rl_f(qry0, i & 63), qyb = rl_f(qry1, i & 63);
        const float qix = (i & 64) ? qxb : qxa;
        const float qiy = (i & 64) ? qyb : qya;

        // ---- specialized first search step: j0 = 0, nothing used ----
        // cur = (cost - u[i+1]) - v with u[i+1] = +0  ->  cost - v (bit-exact)
        float minv0 = (fabsf(qix - tx0) + fabsf(qiy - ty0)) - v0;
        float minv1 = (fabsf(qix - tx1) + fabsf(qiy - ty1)) - v1;
        int   way0 = 0, way1 = 0;
        bool  used0 = false, used1 = false;

        float m     = fminf(minv0, minv1);
        float delta = wave_min_f(m);
        unsigned long long b0 = __ballot(minv0 == delta);
        unsigned long long b1 = __ballot(minv1 == delta);
        int j1 = b0 ? (int)__ffsll((long long)b0) : 64 + (int)__ffsll((long long)b1);

        int  src = (j1 - 1) & 63;
        bool hi  = j1 > 64;
        {
            // stable-source fetch (p/w/qc last written in previous augment)
            int   pa = rl_i(hi ? p1 : p0, src);
            float wa = rl_f(hi ? w1 : w0, src);
            float xa = rl_f(hi ? qcx1 : qcx0, src);
            float ya = rl_f(hi ? qcy1 : qcy0, src);
            int   i0n = pa;
            float u_n = wa;
            float cqx = xa;
            float cqy = ya;

            // step-0 updates: nothing used -> v,w unchanged; minv -= delta
            minv0 -= delta;
            minv1 -= delta;
            float u_row = delta;          // u[i+1] = 0 + delta (exact)
            int   j0    = j1;
            float u_j0  = u_n;

            if (i0n != 0) {
                for (int it = 0; it < NN + 2; ++it) {
                    // mark used[j0] and poison its minv (never read as value)
                    const bool mk0 = (col0 == j0), mk1 = (col1 == j0);
                    used0 |= mk0; used1 |= mk1;
                    minv0 = mk0 ? BIGF : minv0;
                    minv1 = mk1 ? BIGF : minv1;

                    const float cur0 = ((fabsf(cqx - tx0) + fabsf(cqy - ty0)) - u_j0) - v0;
                    const float cur1 = ((fabsf(cqx - tx1) + fabsf(cqy - ty1)) - u_j0) - v1;

                    // way update (guard matches reference; for unused cols
                    // minv == ref minv exactly)
                    if (!used0 && cur0 < minv0) way0 = j0;
                    if (!used1 && cur1 < minv1) way1 = j0;

                    // minv = fminf(masked cur, minv): unused -> ref-exact;
                    // used -> keeps decayed poison (~1e9)
                    minv0 = fminf(used0 ? BIGF : cur0, minv0);
                    minv1 = fminf(used1 ? BIGF : cur1, minv1);

                    // argmin directly on minv (poisoned used cols never win)
                    m     = fminf(minv0, minv1);
                    delta = wave_min_f(m);
                    b0 = __ballot(minv0 == delta);
                    b1 = __ballot(minv1 == delta);
                    j1 = b0 ? (int)__ffsll((long long)b0) : 64 + (int)__ffsll((long long)b1);

                    src = (j1 - 1) & 63;
                    hi  = j1 > 64;
                    i0n = rl_i(hi ? p1 : p0, src);
                    const float u_nn = rl_f(hi ? w1 : w0, src);
                    const float nqx  = rl_f(hi ? qcx1 : qcx0, src);
                    const float nqy  = rl_f(hi ? qcy1 : qcy0, src);

                    // reference-exact dual updates: v -= du, u[p] += du;
                    // minv -= delta unconditional (unused: exact; used: poison)
                    const float td0 = used0 ? delta : 0.f;
                    const float td1 = used1 ? delta : 0.f;
                    v0 -= td0; w0 += td0;
                    v1 -= td1; w1 += td1;
                    minv0 -= delta;
                    minv1 -= delta;
                    u_row += delta;

                    j0 = j1; u_j0 = u_nn; cqx = nqx; cqy = nqy;
                    if (i0n == 0) break;
                }
            }

            // ---- augment: shuffle (p, w, qc) along `way` chain from j0 ----
            int jj = j0;
            for (int it = 0; it <= NN; ++it) {
                const int  wsrc = (jj - 1) & 63;
                const bool whi  = jj > 64;
                const int  wva = rl_i(way0, wsrc), wvb = rl_i(way1, wsrc);
                const int  jn  = whi ? wvb : wva;

                int pn; float wn, xn, yn;
                if (jn == 0) {                      // path root: current row
                    pn = i + 1; wn = u_row; xn = qix; yn = qiy;
                } else {
                    const int  s2 = (jn - 1) & 63;
                    const bool h2 = jn > 64;
                    const int   paa = rl_i(p0, s2),   pbb = rl_i(p1, s2);
                    const float waa = rl_f(w0, s2),   wbb = rl_f(w1, s2);
                    const float xaa = rl_f(qcx0, s2), xbb = rl_f(qcx1, s2);
                    const float yaa = rl_f(qcy0, s2), ybb = rl_f(qcy1, s2);
                    pn = h2 ? pbb : paa; wn = h2 ? wbb : waa;
                    xn = h2 ? xbb : xaa; yn = h2 ? ybb : yaa;
                }
                if (col0 == jj) { p0 = pn; w0 = wn; qcx0 = xn; qcy0 = yn; }
                if (col1 == jj) { p1 = pn; w1 = wn; qcx1 = xn; qcy1 = yn; }
                jj = jn;
                if (jj == 0) break;
            }
        }
    }

    // p_[s] = row matched to column col[s]; out[row] = col (0-indexed)
    out[prob * NN + p0 - 1] = col0 - 1;
    out[prob * NN + p1 - 1] = col1 - 1;
}

extern "C" void kernel_launch(void* const* d_in, const int* in_sizes, int n_in,
                              void* d_out, int out_size, void* d_ws, size_t ws_size,
                              hipStream_t stream) {
    const float* preds   = (const float*)d_in[0];   // (4,8,128,2) fp32
    const float* targets = (const float*)d_in[1];   // (4,8,128,2) fp32
    int* out = (int*)d_out;                         // (4,8,128) int32

    hungarian_kernel<<<32, 64, 0, stream>>>(preds, targets, out);
}